// Round 4
// baseline (268.855 us; speedup 1.0000x reference)
//
#include <hip/hip_runtime.h>
#include <hip/hip_bf16.h>

typedef _Float16 f16;
typedef _Float16 f16x8 __attribute__((ext_vector_type(8)));
typedef short bf16x8 __attribute__((ext_vector_type(8)));
typedef short bf16x4 __attribute__((ext_vector_type(4)));
typedef float f32x4 __attribute__((ext_vector_type(4)));
typedef unsigned int u32;
typedef unsigned short u16;

#define HEADS 32
#define SEQ   2048
#define DIM   64
#define QT    16
#define KT    64
#define NT    32   // SEQ/KT
#define L2E   1.44269504088896340736f

__device__ __forceinline__ void gload_lds16(const void* gsrc, void* ldst) {
  __builtin_amdgcn_global_load_lds((__attribute__((address_space(1))) void*)gsrc,
                                   (__attribute__((address_space(3))) void*)ldst, 16, 0, 0);
}
__device__ __forceinline__ u16 f32_bf16(float x) {
  __hip_bfloat16 h = __float2bfloat16(x);
  return *reinterpret_cast<u16*>(&h);
}
__device__ __forceinline__ float bf16_f32(u16 u) {
  u32 x = (u32)u << 16;
  return __builtin_bit_cast(float, x);
}

// Kernel 0: k -> kt (f16, per-row XOR-swizzled for LDS staging)
//           v -> vt2 (bf16, [h][d][kv'] with kv' = p*128 + qq*32 + tp*16 + off,
//                     kv = (2p+tp)*64 + qq*16 + off)  — PV B-frag contiguous 16B
__global__ __launch_bounds__(256) void prep_kernel(const float* __restrict__ k,
                                                   const float* __restrict__ v,
                                                   char* __restrict__ kt,
                                                   u16* __restrict__ vt2) {
  int n = blockIdx.x * 256 + threadIdx.x;
  const int HALFK = HEADS * SEQ * (DIM / 8);  // 524288
  if (n < HALFK) {
    int d8 = (n & 7) * 8;
    int kv = (n >> 3) & (SEQ - 1);
    int h  = n >> 14;
    const float* src = k + ((size_t)(h * SEQ + kv)) * DIM + d8;
    float4 a = *(const float4*)src;
    float4 b = *(const float4*)(src + 4);
    f16x8 o;
    o[0]=(f16)a.x; o[1]=(f16)a.y; o[2]=(f16)a.z; o[3]=(f16)a.w;
    o[4]=(f16)b.x; o[5]=(f16)b.y; o[6]=(f16)b.z; o[7]=(f16)b.w;
    *(f16x8*)(kt + ((size_t)(h * SEQ + kv)) * 128 + ((d8 * 2) ^ ((kv & 7) << 4))) = o;
  } else {
    int m = n - HALFK;          // [0, 524288)
    int c8 = m & 255;           // kv'/8 within row (SEQ/8 = 256)
    int d  = (m >> 8) & 63;
    int h  = m >> 14;
    int kvp  = c8 * 8;          // kv' base, 8 consecutive
    int off8 = (kvp >> 3) & 1, tp = (kvp >> 4) & 1, qq = (kvp >> 5) & 3, p = kvp >> 7;
    int kv   = (2 * p + tp) * 64 + qq * 16 + off8 * 8;
    const float* src = v + ((size_t)(h * SEQ + kv)) * DIM + d;
    u16 o[8];
#pragma unroll
    for (int j = 0; j < 8; j++) o[j] = f32_bf16(src[j * DIM]);
    *(bf16x8*)(vt2 + ((size_t)(h * DIM + d)) * SEQ + kvp) = *(bf16x8*)o;
  }
}

#define STAGE(t, buf)                                                            \
  do {                                                                           \
    const char* kt_ = kthead + (size_t)(t) * KT * 128;                           \
    gload_lds16(kt_ + tid * 16, &lds_k[buf][tid * 16]);                          \
    gload_lds16(kt_ + 4096 + tid * 16, &lds_k[buf][4096 + tid * 16]);            \
  } while (0)

// QK^T (f16 x32) for kv-quarter qq of tile t (from lds_k[buf]) + exp + bf16 P~ write
#define PROC_TILE(t, buf)                                                        \
  do {                                                                           \
    f32x4 sc = (f32x4){0.f, 0.f, 0.f, 0.f};                                      \
    _Pragma("unroll") for (int kc = 0; kc < 2; kc++) {                           \
      int row_ = qq * 16 + c;                                                    \
      f16x8 kb_ = *(const f16x8*)&lds_k[buf][row_ * 128 +                        \
                     ((kc * 64 + g * 16) ^ ((row_ & 7) << 4))];                  \
      sc = __builtin_amdgcn_mfma_f32_16x16x32_f16(qa[kc], kb_, sc, 0, 0, 0);     \
    }                                                                            \
    _Pragma("unroll") for (int r = 0; r < 4; r++) {                              \
      float e_ = __builtin_amdgcn_exp2f(sc[r] * L2E);                            \
      u16 b_ = f32_bf16(e_);                                                     \
      l_part[r] += bf16_f32(b_);                                                 \
      int row_ = 4 * g + r;                                                      \
      *(u16*)(lds_p + row_ * 4096 + (t) * 128 +                                  \
              ((qq * 32 + c * 2) ^ ((row_ & 7) << 4))) = b_;                     \
    }                                                                            \
  } while (0)

__global__ __launch_bounds__(256, 2) void attn_kernel(const float* __restrict__ q,
                                                      const char* __restrict__ kt,
                                                      const u16* __restrict__ vt2,
                                                      float* __restrict__ out_o,
                                                      float* __restrict__ out_p) {
  __shared__ char lds_p[QT * 4096];   // 64 KB bf16 P~: [row][tile*128 + swz(col)]
  __shared__ char lds_k[2][KT * 128]; // 16 KB K dbuf; reused post-loop for reductions

  const int tid = threadIdx.x;
  const int w = tid >> 6, l = tid & 63, g = l >> 4, c = l & 15;
  const int qq = w;  // wave's kv quarter within each tile

  // XCD-aware bijective swizzle (nwg=4096 % 8 == 0): each XCD gets 4 heads
  int swz  = (blockIdx.x & 7) * 512 + (blockIdx.x >> 3);
  int head = swz >> 7;
  int q0   = (swz & 127) * QT;

  // Q A-fragments (16 rows, shared by all waves)
  f16x8 qa[2];
  {
    const float* qp = q + ((size_t)(head * SEQ + q0 + c)) * DIM + g * 8;
#pragma unroll
    for (int kc = 0; kc < 2; kc++) {
      float4 a = *(const float4*)(qp + kc * 32);
      float4 b = *(const float4*)(qp + kc * 32 + 4);
      qa[kc][0]=(f16)a.x; qa[kc][1]=(f16)a.y; qa[kc][2]=(f16)a.z; qa[kc][3]=(f16)a.w;
      qa[kc][4]=(f16)b.x; qa[kc][5]=(f16)b.y; qa[kc][6]=(f16)b.z; qa[kc][7]=(f16)b.w;
    }
  }

  const char* kthead = kt + (size_t)head * SEQ * 128;
  const u16*  vhead  = vt2 + (size_t)head * DIM * SEQ;

  float l_part[4] = {0.f, 0.f, 0.f, 0.f};
  f32x4 o_acc[4];
#pragma unroll
  for (int dq = 0; dq < 4; dq++) o_acc[dq] = (f32x4){0.f, 0.f, 0.f, 0.f};

  STAGE(0, 0);
  __syncthreads();

  for (int p = 0; p < NT / 2; p++) {
    int t0 = 2 * p;
    STAGE(t0 + 1, 1);
    PROC_TILE(t0, 0);
    // prefetch PV B-frags (V^T bf16, contiguous 16B per lane)
    bf16x8 vb[4];
#pragma unroll
    for (int dq = 0; dq < 4; dq++)
      vb[dq] = *(const bf16x8*)(vhead + (size_t)(dq * 16 + c) * SEQ + p * 128 + qq * 32 + g * 8);
    __syncthreads();
    if (t0 + 2 < NT) STAGE(t0 + 2, 0);
    PROC_TILE(t0 + 1, 1);
    // PV (bf16 x32): A-frag = wave-own P~ rows, k = g*8.. maps to tile 2p+(g>>1)
    {
      int tg = t0 + (g >> 1);
      bf16x8 pa = *(const bf16x8*)(lds_p + c * 4096 + tg * 128 +
                                   ((qq * 32 + (g & 1) * 16) ^ ((c & 7) << 4)));
#pragma unroll
      for (int dq = 0; dq < 4; dq++)
        o_acc[dq] = __builtin_amdgcn_mfma_f32_16x16x32_bf16(pa, vb[dq], o_acc[dq], 0, 0, 0);
    }
    __syncthreads();
  }

  // ---- l reduce: across the 16 lanes of each group, then across the 4 waves
#pragma unroll
  for (int r = 0; r < 4; r++)
#pragma unroll
    for (int d = 1; d < 16; d <<= 1) l_part[r] += __shfl_xor(l_part[r], d, 64);
  float* lred = (float*)lds_k;  // [4 waves][16 rows]
  if (c == 0) {
#pragma unroll
    for (int r = 0; r < 4; r++) lred[w * 16 + 4 * g + r] = l_part[r];
  }
  __syncthreads();
  const int orow = tid >> 4, od0 = (tid & 15) * 4;
  float rinv_o = 1.0f / (lred[orow] + lred[16 + orow] + lred[32 + orow] + lred[48 + orow]);
  float rinv_p[4];
#pragma unroll
  for (int j = 0; j < 4; j++) {
    int rr = w * 4 + j;
    rinv_p[j] = 1.0f / (lred[rr] + lred[16 + rr] + lred[32 + rr] + lred[48 + rr]);
  }
  __syncthreads();

  // ---- O cross-wave reduce through lds_k ([wave][16 rows][64 d] f32)
  float* ored = (float*)lds_k;
#pragma unroll
  for (int dq = 0; dq < 4; dq++)
#pragma unroll
    for (int r = 0; r < 4; r++)
      ored[w * 1024 + (4 * g + r) * 64 + dq * 16 + c] = o_acc[dq][r];
  __syncthreads();
  {
    f32x4 s = *(const f32x4*)&ored[orow * 64 + od0];
    s += *(const f32x4*)&ored[1024 + orow * 64 + od0];
    s += *(const f32x4*)&ored[2048 + orow * 64 + od0];
    s += *(const f32x4*)&ored[3072 + orow * 64 + od0];
    s *= rinv_o;
    __builtin_nontemporal_store(s, (f32x4*)&out_o[(size_t)(head * SEQ + q0 + orow) * DIM + od0]);
  }

  // ---- probs burst: read P~, scale, coalesced f32x4 nt stores
  float* prow = out_p + (size_t)(head * SEQ + q0) * SEQ;
#pragma unroll
  for (int j = 0; j < 4; j++) {
    int row = w * 4 + j;
#pragma unroll
    for (int i = 0; i < 8; i++) {
      bf16x4 pb = *(const bf16x4*)(lds_p + row * 4096 + ((i * 512 + l * 8) ^ ((row & 7) << 4)));
      f32x4 pv;
#pragma unroll
      for (int e = 0; e < 4; e++) pv[e] = bf16_f32((u16)pb[e]) * rinv_p[j];
      __builtin_nontemporal_store(pv, (f32x4*)&prow[(size_t)row * SEQ + i * 256 + l * 4]);
    }
  }
}

extern "C" void kernel_launch(void* const* d_in, const int* in_sizes, int n_in,
                              void* d_out, int out_size, void* d_ws, size_t ws_size,
                              hipStream_t stream) {
  const float* k = (const float*)d_in[0];
  const float* q = (const float*)d_in[1];
  const float* v = (const float*)d_in[2];
  float* out_o = (float*)d_out;
  float* out_p = out_o + (size_t)HEADS * SEQ * DIM;

  char* kt = (char*)d_ws;                                  // 8 MB swizzled f16 K
  u16*  vt2 = (u16*)(kt + (size_t)HEADS * SEQ * DIM * 2);  // 8 MB bf16 V^T (permuted)

  prep_kernel<<<dim3(4096), dim3(256), 0, stream>>>(k, v, kt, vt2);
  attn_kernel<<<dim3(4096), dim3(256), 0, stream>>>(q, kt, vt2, out_o, out_p);
}

// Round 5
// 223.957 us; speedup vs baseline: 1.2005x; 1.2005x over previous
//
#include <hip/hip_runtime.h>

typedef _Float16 f16;
typedef _Float16 f16x8 __attribute__((ext_vector_type(8)));
typedef float f32x4 __attribute__((ext_vector_type(4)));

#define HEADS 32
#define SEQ   2048
#define DIM   64
#define QT    64
#define KT    64
#define NT    32
#define L2E   1.44269504088896340736f

__device__ __forceinline__ void gload_lds16(const void* gsrc, void* ldst) {
  __builtin_amdgcn_global_load_lds((__attribute__((address_space(1))) void*)gsrc,
                                   (__attribute__((address_space(3))) void*)ldst, 16, 0, 0);
}

// k -> kt (f16, per-row XOR-swizzled for linear LDS staging)
// v -> vt (f16 transposed [d][kv])
__global__ __launch_bounds__(256) void prep_kernel(const float* __restrict__ k,
                                                   const float* __restrict__ v,
                                                   char* __restrict__ kt,
                                                   f16* __restrict__ vt) {
  int n = blockIdx.x * 256 + threadIdx.x;
  const int HALF = HEADS * SEQ * (DIM / 8);  // 524288
  if (n < HALF) {
    int d8 = (n & 7) * 8;
    int kv = (n >> 3) & (SEQ - 1);
    int h  = n >> 14;
    const float* src = k + ((size_t)(h * SEQ + kv)) * DIM + d8;
    float4 a = *(const float4*)src;
    float4 b = *(const float4*)(src + 4);
    f16x8 o;
    o[0]=(f16)a.x; o[1]=(f16)a.y; o[2]=(f16)a.z; o[3]=(f16)a.w;
    o[4]=(f16)b.x; o[5]=(f16)b.y; o[6]=(f16)b.z; o[7]=(f16)b.w;
    *(f16x8*)(kt + ((size_t)(h * SEQ + kv)) * 128 + ((d8 * 2) ^ ((kv & 7) << 4))) = o;
  } else {
    int m = n - HALF;
    int d   = m & 63;
    int kv8 = ((m >> 6) & 255) * 8;
    int h   = m >> 14;
    const float* src = v + ((size_t)(h * SEQ + kv8)) * DIM + d;
    f16x8 o;
#pragma unroll
    for (int i = 0; i < 8; i++) o[i] = (f16)src[i * DIM];
    *(f16x8*)(vt + ((size_t)(h * DIM + d)) * SEQ + kv8) = o;
  }
}

#define STAGE(t, buf)                                                                  \
  do {                                                                                 \
    const char* ktile_ = kthead + (size_t)(t) * KT * 128;                              \
    gload_lds16(ktile_ + tid * 16, &lds_k[buf][tid * 16]);                             \
    gload_lds16(ktile_ + 4096 + tid * 16, &lds_k[buf][4096 + tid * 16]);               \
  } while (0)

#define QKT_M(QA, SC, buf)                                                             \
  do {                                                                                 \
    _Pragma("unroll") for (int kc = 0; kc < 2; kc++) {                                 \
      _Pragma("unroll") for (int f = 0; f < 4; f++) {                                  \
        int row_ = f * 16 + c;                                                         \
        f16x8 kb_ = *(const f16x8*)&lds_k[buf][row_ * 128 +                            \
                       ((kc * 64 + g * 16) ^ ((row_ & 7) << 4))];                      \
        SC[f] = __builtin_amdgcn_mfma_f32_16x16x32_f16(QA[kc], kb_, SC[f], 0, 0, 0);   \
      }                                                                                \
    }                                                                                  \
  } while (0)

// pass-2 body for one K-tile: scale -> LDS transpose -> coalesced probs stores -> PV
#define P2_BODY(SC, RINV, PROW, OACC, t)                                               \
  do {                                                                                 \
    _Pragma("unroll") for (int f = 0; f < 4; f++)                                      \
      _Pragma("unroll") for (int r = 0; r < 4; r++) {                                  \
        float pv_ = __builtin_amdgcn_exp2f(SC[f][r] * L2E) * RINV[r];                  \
        int rowL_ = w * 16 + 4 * g + r;                                                \
        lds_pt[rowL_ * 64 + ((16 * f + c) ^ ((rowL_ & 7) << 2))] = pv_;                \
      }                                                                                \
    asm volatile("" ::: "memory");                                                     \
    _Pragma("unroll") for (int j = 0; j < 4; j++) {                                    \
      int rowL_ = w * 16 + j * 4 + g;                                                  \
      f32x4 pv4_ = *(const f32x4*)&lds_pt[rowL_ * 64 + ((c ^ (rowL_ & 7)) << 2)];      \
      __builtin_nontemporal_store(pv4_, (f32x4*)&PROW[(size_t)rowL_ * SEQ + (t) * 64 + c * 4]); \
    }                                                                                  \
    {                                                                                  \
      int rowA_ = w * 16 + c;                                                          \
      int sw_ = c & 7;                                                                 \
      _Pragma("unroll") for (int kc = 0; kc < 2; kc++) {                               \
        f32x4 a0_ = *(const f32x4*)&lds_pt[rowA_ * 64 + (((8 * kc + 2 * g) ^ sw_) << 2)];     \
        f32x4 a1_ = *(const f32x4*)&lds_pt[rowA_ * 64 + (((8 * kc + 2 * g + 1) ^ sw_) << 2)]; \
        f16x8 pa_;                                                                     \
        pa_[0]=(f16)a0_[0]; pa_[1]=(f16)a0_[1]; pa_[2]=(f16)a0_[2]; pa_[3]=(f16)a0_[3];\
        pa_[4]=(f16)a1_[0]; pa_[5]=(f16)a1_[1]; pa_[6]=(f16)a1_[2]; pa_[7]=(f16)a1_[3];\
        _Pragma("unroll") for (int f = 0; f < 4; f++) {                                \
          f16x8 vb_ = *(const f16x8*)(vhead + (size_t)(f * 16 + c) * SEQ + (t) * 64 + kc * 32 + g * 8); \
          OACC[f] = __builtin_amdgcn_mfma_f32_16x16x32_f16(pa_, vb_, OACC[f], 0, 0, 0);\
        }                                                                              \
      }                                                                                \
    }                                                                                  \
  } while (0)

// O epilogue: LDS transpose -> coalesced nt stores (rows wave-private, fence suffices)
#define O_EPI(OACC, ROWOFF)                                                            \
  do {                                                                                 \
    _Pragma("unroll") for (int f = 0; f < 4; f++)                                      \
      _Pragma("unroll") for (int r = 0; r < 4; r++) {                                  \
        int rowL_ = w * 16 + 4 * g + r;                                                \
        lds_pt[rowL_ * 64 + ((16 * f + c) ^ ((rowL_ & 7) << 2))] = OACC[f][r];         \
      }                                                                                \
    asm volatile("" ::: "memory");                                                     \
    _Pragma("unroll") for (int j = 0; j < 4; j++) {                                    \
      int rowL_ = w * 16 + j * 4 + g;                                                  \
      f32x4 ov_ = *(const f32x4*)&lds_pt[rowL_ * 64 + ((c ^ (rowL_ & 7)) << 2)];       \
      __builtin_nontemporal_store(ov_, (f32x4*)&out_o[(size_t)(head * SEQ + (ROWOFF) + rowL_) * DIM + c * 4]); \
    }                                                                                  \
  } while (0)

__global__ __launch_bounds__(256, 2) void attn_kernel(const float* __restrict__ q,
                                                      const char* __restrict__ kt,
                                                      const f16* __restrict__ vt,
                                                      float* __restrict__ out_o,
                                                      float* __restrict__ out_p) {
  __shared__ char  lds_k[2][KT * 128];  // 16 KB K double buffer
  __shared__ float lds_pt[QT * 64];     // 16 KB fp32 transpose buffer (P and O)

  const int tid = threadIdx.x;
  const int w = tid >> 6, l = tid & 63, g = l >> 4, c = l & 15;

  // XCD swizzle: 512 blocks, 64/XCD -> 4 heads per XCD (K+V L2-resident)
  const int swz  = (blockIdx.x & 7) * 64 + (blockIdx.x >> 3);
  const int head = swz >> 4;
  const int q0   = (swz & 15) * 128;  // T0 rows [q0,q0+64), T1 rows [q0+64,q0+128)

  // Q A-fragments for both tiles
  f16x8 qa0[2], qa1[2];
#pragma unroll
  for (int ti = 0; ti < 2; ti++) {
    const float* qp = q + ((size_t)(head * SEQ + q0 + ti * 64 + w * 16 + c)) * DIM + g * 8;
    f16x8* qa = ti ? qa1 : qa0;
#pragma unroll
    for (int kc = 0; kc < 2; kc++) {
      float4 a = *(const float4*)(qp + kc * 32);
      float4 b = *(const float4*)(qp + kc * 32 + 4);
      qa[kc][0]=(f16)a.x; qa[kc][1]=(f16)a.y; qa[kc][2]=(f16)a.z; qa[kc][3]=(f16)a.w;
      qa[kc][4]=(f16)b.x; qa[kc][5]=(f16)b.y; qa[kc][6]=(f16)b.z; qa[kc][7]=(f16)b.w;
    }
  }

  const char* kthead = kt + (size_t)head * SEQ * 128;
  const f16*  vhead  = vt + (size_t)head * DIM * SEQ;

  // ---------- prologue: pass1(T0) — no-max l accumulation ----------
  float l0[4] = {0.f, 0.f, 0.f, 0.f};
  STAGE(0, 0);
  __syncthreads();
  for (int t = 0; t < NT; t++) {
    int cur = t & 1;
    if (t + 1 < NT) STAGE(t + 1, cur ^ 1);
    f32x4 sc[4];
#pragma unroll
    for (int f = 0; f < 4; f++) sc[f] = (f32x4){0.f, 0.f, 0.f, 0.f};
    QKT_M(qa0, sc, cur);
#pragma unroll
    for (int f = 0; f < 4; f++)
#pragma unroll
      for (int r = 0; r < 4; r++) l0[r] += __builtin_amdgcn_exp2f(sc[f][r] * L2E);
    __syncthreads();
  }
  f32x4 rinv0;
#pragma unroll
  for (int r = 0; r < 4; r++) {
    float lv = l0[r];
#pragma unroll
    for (int d = 1; d < 16; d <<= 1) lv += __shfl_xor(lv, d, 64);
    rinv0[r] = 1.0f / lv;
  }

  // ---------- merged: pass2(T0) || pass1(T1), K-tile staged once for both ----------
  f32x4 o_acc0[4], o_acc1[4];
#pragma unroll
  for (int f = 0; f < 4; f++) { o_acc0[f] = (f32x4){0.f,0.f,0.f,0.f}; o_acc1[f] = (f32x4){0.f,0.f,0.f,0.f}; }
  float l1[4] = {0.f, 0.f, 0.f, 0.f};
  float* prow0 = out_p + (size_t)(head * SEQ + q0) * SEQ;

  STAGE(0, 0);
  __syncthreads();
  for (int t = 0; t < NT; t++) {
    int cur = t & 1;
    if (t + 1 < NT) STAGE(t + 1, cur ^ 1);
    f32x4 sc[4];
#pragma unroll
    for (int f = 0; f < 4; f++) sc[f] = (f32x4){0.f, 0.f, 0.f, 0.f};
    QKT_M(qa0, sc, cur);
    P2_BODY(sc, rinv0, prow0, o_acc0, t);
    f32x4 sc2[4];
#pragma unroll
    for (int f = 0; f < 4; f++) sc2[f] = (f32x4){0.f, 0.f, 0.f, 0.f};
    QKT_M(qa1, sc2, cur);
#pragma unroll
    for (int f = 0; f < 4; f++)
#pragma unroll
      for (int r = 0; r < 4; r++) l1[r] += __builtin_amdgcn_exp2f(sc2[f][r] * L2E);
    __syncthreads();
  }
  O_EPI(o_acc0, q0);

  f32x4 rinv1;
#pragma unroll
  for (int r = 0; r < 4; r++) {
    float lv = l1[r];
#pragma unroll
    for (int d = 1; d < 16; d <<= 1) lv += __shfl_xor(lv, d, 64);
    rinv1[r] = 1.0f / lv;
  }

  // ---------- tail: pass2(T1) ----------
  float* prow1 = out_p + (size_t)(head * SEQ + q0 + 64) * SEQ;
  __syncthreads();  // protect lds_pt/lds_k reuse across waves
  STAGE(0, 0);
  __syncthreads();
  for (int t = 0; t < NT; t++) {
    int cur = t & 1;
    if (t + 1 < NT) STAGE(t + 1, cur ^ 1);
    f32x4 sc[4];
#pragma unroll
    for (int f = 0; f < 4; f++) sc[f] = (f32x4){0.f, 0.f, 0.f, 0.f};
    QKT_M(qa1, sc, cur);
    P2_BODY(sc, rinv1, prow1, o_acc1, t);
    __syncthreads();
  }
  O_EPI(o_acc1, q0 + 64);
}

extern "C" void kernel_launch(void* const* d_in, const int* in_sizes, int n_in,
                              void* d_out, int out_size, void* d_ws, size_t ws_size,
                              hipStream_t stream) {
  const float* k = (const float*)d_in[0];
  const float* q = (const float*)d_in[1];
  const float* v = (const float*)d_in[2];
  float* out_o = (float*)d_out;
  float* out_p = out_o + (size_t)HEADS * SEQ * DIM;

  char* kt = (char*)d_ws;                                 // 8 MB swizzled f16 K
  f16*  vt = (f16*)(kt + (size_t)HEADS * SEQ * DIM * 2);  // 8 MB f16 V^T

  prep_kernel<<<dim3(4096), dim3(256), 0, stream>>>(k, v, kt, vt);
  attn_kernel<<<dim3(512), dim3(256), 0, stream>>>(q, kt, vt, out_o, out_p);
}